// Round 12
// baseline (179.018 us; speedup 1.0000x reference)
//
#include <hip/hip_runtime.h>

// ---------------------------------------------------------------------------
// GeneratorInitial via split-f16 MFMA (hi/lo, f32-class accuracy) with the
// depthwise 3x3 folded into conv2 as a per-batch composite 11x11 conv:
//   out = W2 (*) (F_b (*) y1) = Wc_b (*) y1,  Wc_b = F_b (*) W2  (both linear)
//
//   k_prep:    filter MLP -> F_b; Wc_b = F_b (*) W2; emit pre-split per-lane
//              MFMA B-fragments for W1 (9 dy) and Wc_b (11 dy).
//   k_conv1:   in f32 -> 9x9 conv (MFMA) -> relu -> y1 (hi,lo f16 interleaved)
//   k_dwconv2: y1 -> 11x11 per-batch conv (MFMA) -> relu -> pixnorm -> out
//
// MFMA scheme per output row: dy-rowconvs, each M16 x N16 x K64:
//   M = 16 pixel groups (x stride 4), N = (shift s 0..3) x (out ch f 0..3),
//   K = 16 e-positions x 4 in-ch, k = st*32 + 8g + j.  B[k][n] = W[dy][e-s][c][f].
//
// Register plan (R12): THREE-PASS split.  The three precision terms
// (ah*Bh, al*Bh, ah*Bl) each need only ONE B plane and ONE A plane, so run
// them as separate passes per st-half: resident B = 11 frags = 44 VGPR
// (volatile loads so passes can't be CSE-merged into one long live range),
// A read 1 frag per (st,pass,ir) and consumed immediately.  Live set
// ~85-90 VGPR fits the allocator's observed ~80-100 budget (R5-R11: it
// refuses to hold more, spilling/sinking instead; waves_per_eu inert).
// A-LDS reads: 108/wave vs ~352 in the sunk state.  MFMA count unchanged.
// ---------------------------------------------------------------------------

typedef _Float16 f16;
typedef _Float16 f16x2 __attribute__((ext_vector_type(2)));
typedef _Float16 f16x4 __attribute__((ext_vector_type(4)));
typedef _Float16 f16x8 __attribute__((ext_vector_type(8)));
typedef float f32x4 __attribute__((ext_vector_type(4)));

static __device__ __forceinline__ f32x4 mfma16(f16x8 a, f16x8 b, f32x4 c) {
    return __builtin_amdgcn_mfma_f32_16x16x32_f16(a, b, c, 0, 0, 0);
}

static __device__ __forceinline__ float silu_f(float x) {
    return x / (1.0f + expf(-x));
}

// returns (hi, lo) with x ~= hi + lo
static __device__ __forceinline__ f16x2 split_f(float x) {
    f16x2 r;
    r[0] = (f16)x;
    r[1] = (f16)(x - (float)r[0]);
    return r;
}

// --- prep: per-batch filters, composite weights, pre-split B-fragments
//     fragW1: [9][st 2][hl 2][lane 64] f16x8      (batch-independent)
//     fragW2: [16][11][st 2][hl 2][lane 64] f16x8 (per-batch composite)
__global__ __launch_bounds__(256) void k_prep(
    const float* __restrict__ params, const float* __restrict__ W_emb,
    const float* __restrict__ b_emb, const float* __restrict__ KT,
    const float* __restrict__ bT, const float* __restrict__ W1,
    const float* __restrict__ W2,
    f16x8* __restrict__ fragW1, f16x8* __restrict__ fragW2)
{
    __shared__ float s_emb[128];
    __shared__ float s_filt[36];      // [i2*3+j2][c]
    __shared__ float s_wc[1936];      // [dy][dx][c][f], 11x11x4x4
    const int t = threadIdx.x, b = blockIdx.x;

    if (t < 128) {
        float sv = b_emb[t];
#pragma unroll
        for (int p = 0; p < 8; ++p)
            sv = fmaf(params[b * 8 + p], W_emb[p * 128 + t], sv);
        s_emb[t] = silu_f(sv);
    }
    __syncthreads();
    if (t < 36) {
        const int ij = t >> 2, ff = t & 3;
        float sv = bT[ff];
        for (int c = 0; c < 128; ++c)
            sv = fmaf(s_emb[c], KT[(ij * 128 + c) * 4 + ff], sv);
        s_filt[t] = silu_f(sv);
    }
    __syncthreads();

    // composite Wc[dy][dx][c][f] = sum_{i2,j2} F[i2][j2][c] * W2[dy-i2][dx-j2][c][f]
    for (int i = t; i < 1936; i += 256) {
        const int f = i & 3, c = (i >> 2) & 3;
        const int dxy = i >> 4, dx = dxy % 11, dy = dxy / 11;
        float sv = 0.f;
#pragma unroll
        for (int i2 = 0; i2 < 3; ++i2)
#pragma unroll
            for (int j2 = 0; j2 < 3; ++j2) {
                const int a = dy - i2, bb = dx - j2;
                if (a >= 0 && a < 9 && bb >= 0 && bb < 9)
                    sv = fmaf(s_filt[(i2 * 3 + j2) * 4 + c],
                              W2[((a * 9 + bb) * 4 + c) * 4 + f], sv);
            }
        s_wc[i] = sv;
    }
    __syncthreads();

    // B-fragments for the composite (per batch)
    for (int fi = t; fi < 11 * 256; fi += 256) {
        const int dy = fi >> 8, rem = fi & 255;
        const int st = (rem >> 7) & 1, hl = (rem >> 6) & 1, lane = rem & 63;
        const int g = lane >> 4, n = lane & 15, s = n >> 2, f = n & 3;
        f16x8 v;
#pragma unroll
        for (int j = 0; j < 8; ++j) {
            const int k = st * 32 + g * 8 + j;
            const int e = k >> 2, c = k & 3, dx = e - s;
            const float wv = (dx >= 0 && dx < 11)
                ? s_wc[((dy * 11 + dx) * 4 + c) * 4 + f] : 0.f;
            const f16x2 hlv = split_f(wv);
            v[j] = hl ? hlv[1] : hlv[0];
        }
        fragW2[((size_t)b * 11 + dy) * 256 + rem] = v;
    }

    // B-fragments for W1 (batch-independent; block 0 only)
    if (b == 0) {
        for (int fi = t; fi < 9 * 256; fi += 256) {
            const int dy = fi >> 8, rem = fi & 255;
            const int st = (rem >> 7) & 1, hl = (rem >> 6) & 1, lane = rem & 63;
            const int g = lane >> 4, n = lane & 15, s = n >> 2, f = n & 3;
            f16x8 v;
#pragma unroll
            for (int j = 0; j < 8; ++j) {
                const int k = st * 32 + g * 8 + j;
                const int e = k >> 2, c = k & 3, dx = e - s;
                const float wv = (dx >= 0 && dx < 9)
                    ? W1[((dy * 9 + dx) * 4 + c) * 4 + f] : 0.f;
                const f16x2 hlv = split_f(wv);
                v[j] = hl ? hlv[1] : hlv[0];
            }
            fragW1[(size_t)dy * 256 + rem] = v;
        }
    }
}

// --- conv1: [16,512,512,4] f32 -> relu -> y1 [16,504,504] x (h,l)x4 f16
__global__ __launch_bounds__(256, 2) void k_conv1(
    const float* __restrict__ in, const float* __restrict__ b1,
    const f16x8* __restrict__ fragW1, f16* __restrict__ y1)
{
    __shared__ f16x4 s_hi[40][76];
    __shared__ f16x4 s_lo[40][76];
    const int t = threadIdx.x;
    const int x0 = blockIdx.x * 64, y0 = blockIdx.y * 32, b = blockIdx.z;

    const float4* inp = (const float4*)in + (size_t)b * (512 * 512);
    for (int i = t; i < 40 * 76; i += 256) {
        const int rr = i / 76, cc = i % 76;
        const int gy = y0 + rr, gx = x0 + cc;
        float4 v = make_float4(0.f, 0.f, 0.f, 0.f);
        if (gy < 512 && gx < 512) v = inp[gy * 512 + gx];
        f16x4 h, l;
        const f16x2 p0 = split_f(v.x), p1 = split_f(v.y);
        const f16x2 p2 = split_f(v.z), p3 = split_f(v.w);
        h[0] = p0[0]; l[0] = p0[1]; h[1] = p1[0]; l[1] = p1[1];
        h[2] = p2[0]; l[2] = p2[1]; h[3] = p3[0]; l[3] = p3[1];
        s_hi[rr][cc] = h; s_lo[rr][cc] = l;
    }

    const int lane = t & 63, w = t >> 6;
    const int g = lane >> 4, n = lane & 15, s = n >> 2, f = n & 3;

    __syncthreads();

    const float bias = b1[f];
    f32x4 acc[8];
#pragma unroll
    for (int r = 0; r < 8; ++r) acc[r] = (f32x4){bias, bias, bias, bias};

    const int ai = 4 * (lane & 15) + 2 * g;
#pragma unroll
    for (int st = 0; st < 2; ++st) {
        const f16x8* bbase = fragW1 + st * 128 + lane;
        // 3 passes: {ah*Bh, al*Bh, ah*Bl}; resident B = 9 frags (36 VGPR)
#pragma unroll
        for (int pass = 0; pass < 3; ++pass) {
            const f16x8* bsrc = bbase + (pass == 2 ? 64 : 0);  // Bl at +64
            f16x8 B[9];
#pragma unroll
            for (int dy = 0; dy < 9; ++dy)
                B[dy] = *(volatile const f16x8*)(bsrc + dy * 256);
            const f16x4 (*aplane)[76] = (pass == 1) ? s_lo : s_hi;
#pragma unroll
            for (int ir = 0; ir < 16; ++ir) {
                const f16x8 A =
                    *(const f16x8*)(&aplane[w * 8 + ir][0] + ai + st * 8);
#pragma unroll
                for (int r = 0; r < 8; ++r) {
                    const int dy = ir - r;
                    if (dy >= 0 && dy < 9) acc[r] = mfma16(A, B[dy], acc[r]);
                }
            }
        }
    }

    // D: col n=(s,f); row m=4g+q; x = x0+16g+4q+s; store (h,l) f16x2
    const int xb = x0 + 16 * g + s;
#pragma unroll
    for (int r = 0; r < 8; ++r) {
        const int yr = y0 + w * 8 + r;
        if (yr >= 504) continue;
        const size_t rowbase = ((size_t)(b * 504 + yr) * 504) * 8 + f * 2;
#pragma unroll
        for (int q = 0; q < 4; ++q) {
            const int x = xb + 4 * q;
            if (x < 504) {
                const float v = fmaxf(acc[r][q], 0.f);
                *(f16x2*)(y1 + rowbase + (size_t)x * 8) = split_f(v);
            }
        }
    }
}

// --- composite 11x11 per-batch conv on y1 + relu + pixnorm -> out f32
__global__ __launch_bounds__(256, 2) void k_dwconv2(
    const f16* __restrict__ y1, const float* __restrict__ b2,
    const f16x8* __restrict__ fragW2, float* __restrict__ out)
{
    __shared__ f16x4 s_hi[42][76];
    __shared__ f16x4 s_lo[42][76];
    const int t = threadIdx.x;
    const int x0 = blockIdx.x * 64, y0 = blockIdx.y * 32, b = blockIdx.z;

    // stage y1 with halo (-1 .. +9 beyond tile), zero outside [0,504)^2
    for (int i = t; i < 42 * 76; i += 256) {
        const int rr = i / 76, cc = i % 76;
        const int gy = y0 - 1 + rr, gx = x0 - 1 + cc;
        f16x4 h, l;
        if (gy >= 0 && gy < 504 && gx >= 0 && gx < 504) {
            const f16x8 p = *(const f16x8*)(y1 + ((size_t)(b * 504 + gy) * 504 +
                                                  (size_t)gx) * 8);
            h[0] = p[0]; l[0] = p[1]; h[1] = p[2]; l[1] = p[3];
            h[2] = p[4]; l[2] = p[5]; h[3] = p[6]; l[3] = p[7];
        } else {
            h[0] = h[1] = h[2] = h[3] = (f16)0.f;
            l[0] = l[1] = l[2] = l[3] = (f16)0.f;
        }
        s_hi[rr][cc] = h; s_lo[rr][cc] = l;
    }

    const int lane = t & 63, w = t >> 6;
    const int g = lane >> 4, n = lane & 15, s = n >> 2, f = n & 3;
    const f16x8* fr = fragW2 + (size_t)b * 11 * 256;

    __syncthreads();

    const float bias = b2[f];
    f32x4 acc[8];
#pragma unroll
    for (int r = 0; r < 8; ++r) acc[r] = (f32x4){bias, bias, bias, bias};

    const int ai = 4 * (lane & 15) + 2 * g;
#pragma unroll
    for (int st = 0; st < 2; ++st) {
        const f16x8* bbase = fr + st * 128 + lane;
        // 3 passes: {ah*Bh, al*Bh, ah*Bl}; resident B = 11 frags (44 VGPR)
#pragma unroll
        for (int pass = 0; pass < 3; ++pass) {
            const f16x8* bsrc = bbase + (pass == 2 ? 64 : 0);  // Bl at +64
            f16x8 B[11];
#pragma unroll
            for (int dy = 0; dy < 11; ++dy)
                B[dy] = *(volatile const f16x8*)(bsrc + dy * 256);
            const f16x4 (*aplane)[76] = (pass == 1) ? s_lo : s_hi;
#pragma unroll
            for (int ir = 0; ir < 18; ++ir) {
                const f16x8 A =
                    *(const f16x8*)(&aplane[w * 8 + ir][0] + ai + st * 8);
#pragma unroll
                for (int r = 0; r < 8; ++r) {
                    const int dy = ir - r;
                    if (dy >= 0 && dy < 11) acc[r] = mfma16(A, B[dy], acc[r]);
                }
            }
        }
    }

    // epilogue: relu -> pixnorm across channels (lanes n^1, n^2) -> f32 store
    const int xb = x0 + 16 * g + s;
#pragma unroll
    for (int r = 0; r < 8; ++r) {
        const int yr = y0 + w * 8 + r;
        const size_t rowbase = ((size_t)((size_t)b * 496 + yr) * 496) * 4 + f;
#pragma unroll
        for (int q = 0; q < 4; ++q) {
            float v = fmaxf(acc[r][q], 0.f);
            float sq = v * v;
            sq += __shfl_xor(sq, 1);
            sq += __shfl_xor(sq, 2);
            const float sc = rsqrtf(sq * 0.25f + 1e-8f);
            const int x = xb + 4 * q;
            if (yr < 496 && x < 496) out[rowbase + (size_t)x * 4] = v * sc;
        }
    }
}

extern "C" void kernel_launch(void* const* d_in, const int* in_sizes, int n_in,
                              void* d_out, int out_size, void* d_ws, size_t ws_size,
                              hipStream_t stream)
{
    const float* noise  = (const float*)d_in[0];
    const float* params = (const float*)d_in[1];
    const float* W_emb  = (const float*)d_in[2];
    const float* b_emb  = (const float*)d_in[3];
    const float* KT     = (const float*)d_in[4];
    const float* bT     = (const float*)d_in[5];
    const float* W1     = (const float*)d_in[6];
    const float* b1     = (const float*)d_in[7];
    const float* W2     = (const float*)d_in[8];
    const float* b2     = (const float*)d_in[9];

    float* out = (float*)d_out;
    f16*   y1  = (f16*)d_ws;  // 16*504*504*8 f16 = 65,028,096 B
    f16x8* fragW2 = (f16x8*)((char*)d_ws + 65028096);           // 720,896 B
    f16x8* fragW1 = (f16x8*)((char*)d_ws + 65028096 + 720896);  //  36,864 B

    k_prep<<<dim3(16), dim3(256), 0, stream>>>(params, W_emb, b_emb, KT, bT,
                                               W1, W2, fragW1, fragW2);

    dim3 grid(8, 16, 16);   // ceil(504/64), ceil(504/32), B
    k_conv1<<<grid, dim3(256), 0, stream>>>(noise, b1, fragW1, y1);

    dim3 grid2(8, 16, 16);  // ceil(496/64), ceil(496/32), B
    k_dwconv2<<<grid2, dim3(256), 0, stream>>>(y1, b2, fragW2, out);
}

// Round 13
// 133.146 us; speedup vs baseline: 1.3445x; 1.3445x over previous
//
#include <hip/hip_runtime.h>

// ---------------------------------------------------------------------------
// GeneratorInitial via split-f16 MFMA (hi/lo, f32-class accuracy) with the
// depthwise 3x3 folded into conv2 as a per-batch composite 11x11 conv:
//   out = W2 (*) (F_b (*) y1) = Wc_b (*) y1,  Wc_b = F_b (*) W2  (both linear)
//
//   k_prep:    filter MLP -> F_b; Wc_b = F_b (*) W2; emit pre-split per-lane
//              MFMA B-fragments for W1 (9 dy) and Wc_b (11 dy).
//   k_conv1:   in f32 -> 9x9 conv (MFMA) -> relu -> y1 (hi,lo f16 interleaved)
//   k_dwconv2: y1 -> 11x11 per-batch conv (MFMA) -> relu -> pixnorm -> out
//
// MFMA scheme per output row: dy-rowconvs, each M16 x N16 x K64:
//   M = 16 pixel groups (x stride 4), N = (shift s 0..3) x (out ch f 0..3),
//   K = 16 e-positions x 4 in-ch, k = st*32 + 8g + j.  B[k][n] = W[dy][e-s][c][f].
//
// Register plan (R13): dy-CHUNKED ir-major.  Evidence R5-R12: volatile loads
// get crushed to ~70-80 VGPR + scratch; plain loads get granted up to ~116.
// So: chunks of <=4 dy -> resident B = 8 frags = 32 VGPR (plain loads),
// ir-major A = 2 frags consumed immediately (minimal LDS traffic), live set
// ~90 < 116.  If the allocator still sinks B, sunk B re-reads hit the
// vmem/L2 pipe -- NOT the LDS pipe carrying A (R6/R8's 86us serialized
// everything on LDS).  MFMA count unchanged; acc carries across chunks.
// ---------------------------------------------------------------------------

typedef _Float16 f16;
typedef _Float16 f16x2 __attribute__((ext_vector_type(2)));
typedef _Float16 f16x4 __attribute__((ext_vector_type(4)));
typedef _Float16 f16x8 __attribute__((ext_vector_type(8)));
typedef float f32x4 __attribute__((ext_vector_type(4)));

static __device__ __forceinline__ f32x4 mfma16(f16x8 a, f16x8 b, f32x4 c) {
    return __builtin_amdgcn_mfma_f32_16x16x32_f16(a, b, c, 0, 0, 0);
}

static __device__ __forceinline__ float silu_f(float x) {
    return x / (1.0f + expf(-x));
}

// returns (hi, lo) with x ~= hi + lo
static __device__ __forceinline__ f16x2 split_f(float x) {
    f16x2 r;
    r[0] = (f16)x;
    r[1] = (f16)(x - (float)r[0]);
    return r;
}

// One dy-chunk [D0, D0+ND): load B (plain), stream A ir-major, 3-term MFMA.
// ROWS = LDS row stride type; all indices compile-time after unroll.
template <int D0, int ND>
static __device__ __forceinline__ void conv_chunk(
    const f16x8* __restrict__ bbase, const f16x4 (*__restrict__ s_hi)[76],
    const f16x4 (*__restrict__ s_lo)[76], const int wrow, const int aoff,
    f32x4* __restrict__ acc)
{
    f16x8 Bh[ND], Bl[ND];
#pragma unroll
    for (int j = 0; j < ND; ++j) {
        Bh[j] = bbase[(D0 + j) * 256];
        Bl[j] = bbase[(D0 + j) * 256 + 64];
    }
#pragma unroll
    for (int ir = D0; ir < D0 + ND + 7; ++ir) {
        const f16x8 Ah = *(const f16x8*)(&s_hi[wrow + ir][0] + aoff);
        const f16x8 Al = *(const f16x8*)(&s_lo[wrow + ir][0] + aoff);
#pragma unroll
        for (int r = 0; r < 8; ++r) {
            const int dy = ir - r;
            if (dy >= D0 && dy < D0 + ND) {
                acc[r] = mfma16(Ah, Bh[dy - D0], acc[r]);
                acc[r] = mfma16(Ah, Bl[dy - D0], acc[r]);
                acc[r] = mfma16(Al, Bh[dy - D0], acc[r]);
            }
        }
    }
}

// --- prep: per-batch filters, composite weights, pre-split B-fragments
//     fragW1: [9][st 2][hl 2][lane 64] f16x8      (batch-independent)
//     fragW2: [16][11][st 2][hl 2][lane 64] f16x8 (per-batch composite)
__global__ __launch_bounds__(256) void k_prep(
    const float* __restrict__ params, const float* __restrict__ W_emb,
    const float* __restrict__ b_emb, const float* __restrict__ KT,
    const float* __restrict__ bT, const float* __restrict__ W1,
    const float* __restrict__ W2,
    f16x8* __restrict__ fragW1, f16x8* __restrict__ fragW2)
{
    __shared__ float s_emb[128];
    __shared__ float s_filt[36];      // [i2*3+j2][c]
    __shared__ float s_wc[1936];      // [dy][dx][c][f], 11x11x4x4
    const int t = threadIdx.x, b = blockIdx.x;

    if (t < 128) {
        float sv = b_emb[t];
#pragma unroll
        for (int p = 0; p < 8; ++p)
            sv = fmaf(params[b * 8 + p], W_emb[p * 128 + t], sv);
        s_emb[t] = silu_f(sv);
    }
    __syncthreads();
    if (t < 36) {
        const int ij = t >> 2, ff = t & 3;
        float sv = bT[ff];
        for (int c = 0; c < 128; ++c)
            sv = fmaf(s_emb[c], KT[(ij * 128 + c) * 4 + ff], sv);
        s_filt[t] = silu_f(sv);
    }
    __syncthreads();

    // composite Wc[dy][dx][c][f] = sum_{i2,j2} F[i2][j2][c] * W2[dy-i2][dx-j2][c][f]
    for (int i = t; i < 1936; i += 256) {
        const int f = i & 3, c = (i >> 2) & 3;
        const int dxy = i >> 4, dx = dxy % 11, dy = dxy / 11;
        float sv = 0.f;
#pragma unroll
        for (int i2 = 0; i2 < 3; ++i2)
#pragma unroll
            for (int j2 = 0; j2 < 3; ++j2) {
                const int a = dy - i2, bb = dx - j2;
                if (a >= 0 && a < 9 && bb >= 0 && bb < 9)
                    sv = fmaf(s_filt[(i2 * 3 + j2) * 4 + c],
                              W2[((a * 9 + bb) * 4 + c) * 4 + f], sv);
            }
        s_wc[i] = sv;
    }
    __syncthreads();

    // B-fragments for the composite (per batch)
    for (int fi = t; fi < 11 * 256; fi += 256) {
        const int dy = fi >> 8, rem = fi & 255;
        const int st = (rem >> 7) & 1, hl = (rem >> 6) & 1, lane = rem & 63;
        const int g = lane >> 4, n = lane & 15, s = n >> 2, f = n & 3;
        f16x8 v;
#pragma unroll
        for (int j = 0; j < 8; ++j) {
            const int k = st * 32 + g * 8 + j;
            const int e = k >> 2, c = k & 3, dx = e - s;
            const float wv = (dx >= 0 && dx < 11)
                ? s_wc[((dy * 11 + dx) * 4 + c) * 4 + f] : 0.f;
            const f16x2 hlv = split_f(wv);
            v[j] = hl ? hlv[1] : hlv[0];
        }
        fragW2[((size_t)b * 11 + dy) * 256 + rem] = v;
    }

    // B-fragments for W1 (batch-independent; block 0 only)
    if (b == 0) {
        for (int fi = t; fi < 9 * 256; fi += 256) {
            const int dy = fi >> 8, rem = fi & 255;
            const int st = (rem >> 7) & 1, hl = (rem >> 6) & 1, lane = rem & 63;
            const int g = lane >> 4, n = lane & 15, s = n >> 2, f = n & 3;
            f16x8 v;
#pragma unroll
            for (int j = 0; j < 8; ++j) {
                const int k = st * 32 + g * 8 + j;
                const int e = k >> 2, c = k & 3, dx = e - s;
                const float wv = (dx >= 0 && dx < 9)
                    ? W1[((dy * 9 + dx) * 4 + c) * 4 + f] : 0.f;
                const f16x2 hlv = split_f(wv);
                v[j] = hl ? hlv[1] : hlv[0];
            }
            fragW1[(size_t)dy * 256 + rem] = v;
        }
    }
}

// --- conv1: [16,512,512,4] f32 -> relu -> y1 [16,504,504] x (h,l)x4 f16
__global__ __launch_bounds__(256, 2) void k_conv1(
    const float* __restrict__ in, const float* __restrict__ b1,
    const f16x8* __restrict__ fragW1, f16* __restrict__ y1)
{
    __shared__ f16x4 s_hi[40][76];
    __shared__ f16x4 s_lo[40][76];
    const int t = threadIdx.x;
    const int x0 = blockIdx.x * 64, y0 = blockIdx.y * 32, b = blockIdx.z;

    const float4* inp = (const float4*)in + (size_t)b * (512 * 512);
    for (int i = t; i < 40 * 76; i += 256) {
        const int rr = i / 76, cc = i % 76;
        const int gy = y0 + rr, gx = x0 + cc;
        float4 v = make_float4(0.f, 0.f, 0.f, 0.f);
        if (gy < 512 && gx < 512) v = inp[gy * 512 + gx];
        f16x4 h, l;
        const f16x2 p0 = split_f(v.x), p1 = split_f(v.y);
        const f16x2 p2 = split_f(v.z), p3 = split_f(v.w);
        h[0] = p0[0]; l[0] = p0[1]; h[1] = p1[0]; l[1] = p1[1];
        h[2] = p2[0]; l[2] = p2[1]; h[3] = p3[0]; l[3] = p3[1];
        s_hi[rr][cc] = h; s_lo[rr][cc] = l;
    }

    const int lane = t & 63, w = t >> 6;
    const int g = lane >> 4, n = lane & 15, s = n >> 2, f = n & 3;

    __syncthreads();

    const float bias = b1[f];
    f32x4 acc[8];
#pragma unroll
    for (int r = 0; r < 8; ++r) acc[r] = (f32x4){bias, bias, bias, bias};

    const int ai = 4 * (lane & 15) + 2 * g;
#pragma unroll
    for (int st = 0; st < 2; ++st) {
        const f16x8* bbase = fragW1 + st * 128 + lane;
        const int aoff = ai + st * 8;
        conv_chunk<0, 5>(bbase, s_hi, s_lo, w * 8, aoff, acc);
        conv_chunk<5, 4>(bbase, s_hi, s_lo, w * 8, aoff, acc);
    }

    // D: col n=(s,f); row m=4g+q; x = x0+16g+4q+s; store (h,l) f16x2
    const int xb = x0 + 16 * g + s;
#pragma unroll
    for (int r = 0; r < 8; ++r) {
        const int yr = y0 + w * 8 + r;
        if (yr >= 504) continue;
        const size_t rowbase = ((size_t)(b * 504 + yr) * 504) * 8 + f * 2;
#pragma unroll
        for (int q = 0; q < 4; ++q) {
            const int x = xb + 4 * q;
            if (x < 504) {
                const float v = fmaxf(acc[r][q], 0.f);
                *(f16x2*)(y1 + rowbase + (size_t)x * 8) = split_f(v);
            }
        }
    }
}

// --- composite 11x11 per-batch conv on y1 + relu + pixnorm -> out f32
__global__ __launch_bounds__(256, 2) void k_dwconv2(
    const f16* __restrict__ y1, const float* __restrict__ b2,
    const f16x8* __restrict__ fragW2, float* __restrict__ out)
{
    __shared__ f16x4 s_hi[42][76];
    __shared__ f16x4 s_lo[42][76];
    const int t = threadIdx.x;
    const int x0 = blockIdx.x * 64, y0 = blockIdx.y * 32, b = blockIdx.z;

    // stage y1 with halo (-1 .. +9 beyond tile), zero outside [0,504)^2
    for (int i = t; i < 42 * 76; i += 256) {
        const int rr = i / 76, cc = i % 76;
        const int gy = y0 - 1 + rr, gx = x0 - 1 + cc;
        f16x4 h, l;
        if (gy >= 0 && gy < 504 && gx >= 0 && gx < 504) {
            const f16x8 p = *(const f16x8*)(y1 + ((size_t)(b * 504 + gy) * 504 +
                                                  (size_t)gx) * 8);
            h[0] = p[0]; l[0] = p[1]; h[1] = p[2]; l[1] = p[3];
            h[2] = p[4]; l[2] = p[5]; h[3] = p[6]; l[3] = p[7];
        } else {
            h[0] = h[1] = h[2] = h[3] = (f16)0.f;
            l[0] = l[1] = l[2] = l[3] = (f16)0.f;
        }
        s_hi[rr][cc] = h; s_lo[rr][cc] = l;
    }

    const int lane = t & 63, w = t >> 6;
    const int g = lane >> 4, n = lane & 15, s = n >> 2, f = n & 3;
    const f16x8* fr = fragW2 + (size_t)b * 11 * 256;

    __syncthreads();

    const float bias = b2[f];
    f32x4 acc[8];
#pragma unroll
    for (int r = 0; r < 8; ++r) acc[r] = (f32x4){bias, bias, bias, bias};

    const int ai = 4 * (lane & 15) + 2 * g;
#pragma unroll
    for (int st = 0; st < 2; ++st) {
        const f16x8* bbase = fr + st * 128 + lane;
        const int aoff = ai + st * 8;
        conv_chunk<0, 4>(bbase, s_hi, s_lo, w * 8, aoff, acc);
        conv_chunk<4, 4>(bbase, s_hi, s_lo, w * 8, aoff, acc);
        conv_chunk<8, 3>(bbase, s_hi, s_lo, w * 8, aoff, acc);
    }

    // epilogue: relu -> pixnorm across channels (lanes n^1, n^2) -> f32 store
    const int xb = x0 + 16 * g + s;
#pragma unroll
    for (int r = 0; r < 8; ++r) {
        const int yr = y0 + w * 8 + r;
        const size_t rowbase = ((size_t)((size_t)b * 496 + yr) * 496) * 4 + f;
#pragma unroll
        for (int q = 0; q < 4; ++q) {
            float v = fmaxf(acc[r][q], 0.f);
            float sq = v * v;
            sq += __shfl_xor(sq, 1);
            sq += __shfl_xor(sq, 2);
            const float sc = rsqrtf(sq * 0.25f + 1e-8f);
            const int x = xb + 4 * q;
            if (yr < 496 && x < 496) out[rowbase + (size_t)x * 4] = v * sc;
        }
    }
}

extern "C" void kernel_launch(void* const* d_in, const int* in_sizes, int n_in,
                              void* d_out, int out_size, void* d_ws, size_t ws_size,
                              hipStream_t stream)
{
    const float* noise  = (const float*)d_in[0];
    const float* params = (const float*)d_in[1];
    const float* W_emb  = (const float*)d_in[2];
    const float* b_emb  = (const float*)d_in[3];
    const float* KT     = (const float*)d_in[4];
    const float* bT     = (const float*)d_in[5];
    const float* W1     = (const float*)d_in[6];
    const float* b1     = (const float*)d_in[7];
    const float* W2     = (const float*)d_in[8];
    const float* b2     = (const float*)d_in[9];

    float* out = (float*)d_out;
    f16*   y1  = (f16*)d_ws;  // 16*504*504*8 f16 = 65,028,096 B
    f16x8* fragW2 = (f16x8*)((char*)d_ws + 65028096);           // 720,896 B
    f16x8* fragW1 = (f16x8*)((char*)d_ws + 65028096 + 720896);  //  36,864 B

    k_prep<<<dim3(16), dim3(256), 0, stream>>>(params, W_emb, b_emb, KT, bT,
                                               W1, W2, fragW1, fragW2);

    dim3 grid(8, 16, 16);   // ceil(504/64), ceil(504/32), B
    k_conv1<<<grid, dim3(256), 0, stream>>>(noise, b1, fragW1, y1);

    dim3 grid2(8, 16, 16);  // ceil(496/64), ceil(496/32), B
    k_dwconv2<<<grid2, dim3(256), 0, stream>>>(y1, b2, fragW2, out);
}

// Round 14
// 129.380 us; speedup vs baseline: 1.3837x; 1.0291x over previous
//
#include <hip/hip_runtime.h>

// ---------------------------------------------------------------------------
// GeneratorInitial via split-f16 MFMA (hi/lo, f32-class accuracy) with the
// depthwise 3x3 folded into conv2 as a per-batch composite 11x11 conv:
//   out = W2 (*) (F_b (*) y1) = Wc_b (*) y1,  Wc_b = F_b (*) W2  (both linear)
//
//   k_prep:    filter MLP -> F_b; Wc_b = F_b (*) W2; emit pre-split per-lane
//              MFMA B-fragments for W1 (9 dy) and Wc_b (11 dy).
//   k_conv1:   in f32 -> 9x9 conv (MFMA) -> relu -> y1 (hi,lo f16 interleaved)
//   k_dwconv2: y1 -> 11x11 per-batch conv (MFMA) -> relu -> pixnorm -> out
//
// MFMA scheme per output row: dy-rowconvs, each M16 x N16 x K64:
//   M = 16 pixel groups (x stride 4), N = (shift s 0..3) x (out ch f 0..3),
//   K = 16 e-positions x 4 in-ch, k = st*32 + 8g + j.  B[k][n] = W[dy][e-s][c][f].
//
// R14: R13's dy-chunked ir-major structure (best so far: no spill, no mass
// re-read) + OCCUPANCY: 16-row tiles cut LDS to ~30KB -> 5 blocks/CU
// (20 waves vs 12; R13 measured Occupancy 28%, MfmaUtil 35% -- latency-bound,
// not pipe-bound).  acc shrinks to 4 rows/wave (16 VGPR), live set ~70 well
// under the allocator's ~80 grant.  s_setprio(1) around MFMA clusters (T5;
// independent blocks at staggered phases).  Floors: dwconv2 ~39us, conv1
// ~28us MFMA-busy at the 3-term split.
// ---------------------------------------------------------------------------

typedef _Float16 f16;
typedef _Float16 f16x2 __attribute__((ext_vector_type(2)));
typedef _Float16 f16x4 __attribute__((ext_vector_type(4)));
typedef _Float16 f16x8 __attribute__((ext_vector_type(8)));
typedef float f32x4 __attribute__((ext_vector_type(4)));

static __device__ __forceinline__ f32x4 mfma16(f16x8 a, f16x8 b, f32x4 c) {
    return __builtin_amdgcn_mfma_f32_16x16x32_f16(a, b, c, 0, 0, 0);
}

static __device__ __forceinline__ float silu_f(float x) {
    return x / (1.0f + expf(-x));
}

// returns (hi, lo) with x ~= hi + lo
static __device__ __forceinline__ f16x2 split_f(float x) {
    f16x2 r;
    r[0] = (f16)x;
    r[1] = (f16)(x - (float)r[0]);
    return r;
}

// One dy-chunk [D0, D0+ND): load B (plain), stream A ir-major, 3-term MFMA.
// 4 output rows per wave (acc[4]).  All indices compile-time after unroll.
template <int D0, int ND, int ROWS>
static __device__ __forceinline__ void conv_chunk4(
    const f16x8* __restrict__ bbase, const f16x4 (*__restrict__ s_hi)[76],
    const f16x4 (*__restrict__ s_lo)[76], const int wrow, const int aoff,
    f32x4* __restrict__ acc)
{
    f16x8 Bh[ND], Bl[ND];
#pragma unroll
    for (int j = 0; j < ND; ++j) {
        Bh[j] = bbase[(D0 + j) * 256];
        Bl[j] = bbase[(D0 + j) * 256 + 64];
    }
    __builtin_amdgcn_s_setprio(1);
#pragma unroll
    for (int ir = D0; ir < D0 + ND + 3; ++ir) {
        const f16x8 Ah = *(const f16x8*)(&s_hi[wrow + ir][0] + aoff);
        const f16x8 Al = *(const f16x8*)(&s_lo[wrow + ir][0] + aoff);
#pragma unroll
        for (int r = 0; r < 4; ++r) {
            const int dy = ir - r;
            if (dy >= D0 && dy < D0 + ND) {
                acc[r] = mfma16(Ah, Bh[dy - D0], acc[r]);
                acc[r] = mfma16(Ah, Bl[dy - D0], acc[r]);
                acc[r] = mfma16(Al, Bh[dy - D0], acc[r]);
            }
        }
    }
    __builtin_amdgcn_s_setprio(0);
    (void)sizeof(char[ROWS]);  // silence unused template param
}

// --- prep: per-batch filters, composite weights, pre-split B-fragments
//     fragW1: [9][st 2][hl 2][lane 64] f16x8      (batch-independent)
//     fragW2: [16][11][st 2][hl 2][lane 64] f16x8 (per-batch composite)
__global__ __launch_bounds__(256) void k_prep(
    const float* __restrict__ params, const float* __restrict__ W_emb,
    const float* __restrict__ b_emb, const float* __restrict__ KT,
    const float* __restrict__ bT, const float* __restrict__ W1,
    const float* __restrict__ W2,
    f16x8* __restrict__ fragW1, f16x8* __restrict__ fragW2)
{
    __shared__ float s_emb[128];
    __shared__ float s_filt[36];      // [i2*3+j2][c]
    __shared__ float s_wc[1936];      // [dy][dx][c][f], 11x11x4x4
    const int t = threadIdx.x, b = blockIdx.x;

    if (t < 128) {
        float sv = b_emb[t];
#pragma unroll
        for (int p = 0; p < 8; ++p)
            sv = fmaf(params[b * 8 + p], W_emb[p * 128 + t], sv);
        s_emb[t] = silu_f(sv);
    }
    __syncthreads();
    if (t < 36) {
        const int ij = t >> 2, ff = t & 3;
        float sv = bT[ff];
        for (int c = 0; c < 128; ++c)
            sv = fmaf(s_emb[c], KT[(ij * 128 + c) * 4 + ff], sv);
        s_filt[t] = silu_f(sv);
    }
    __syncthreads();

    // composite Wc[dy][dx][c][f] = sum_{i2,j2} F[i2][j2][c] * W2[dy-i2][dx-j2][c][f]
    for (int i = t; i < 1936; i += 256) {
        const int f = i & 3, c = (i >> 2) & 3;
        const int dxy = i >> 4, dx = dxy % 11, dy = dxy / 11;
        float sv = 0.f;
#pragma unroll
        for (int i2 = 0; i2 < 3; ++i2)
#pragma unroll
            for (int j2 = 0; j2 < 3; ++j2) {
                const int a = dy - i2, bb = dx - j2;
                if (a >= 0 && a < 9 && bb >= 0 && bb < 9)
                    sv = fmaf(s_filt[(i2 * 3 + j2) * 4 + c],
                              W2[((a * 9 + bb) * 4 + c) * 4 + f], sv);
            }
        s_wc[i] = sv;
    }
    __syncthreads();

    // B-fragments for the composite (per batch)
    for (int fi = t; fi < 11 * 256; fi += 256) {
        const int dy = fi >> 8, rem = fi & 255;
        const int st = (rem >> 7) & 1, hl = (rem >> 6) & 1, lane = rem & 63;
        const int g = lane >> 4, n = lane & 15, s = n >> 2, f = n & 3;
        f16x8 v;
#pragma unroll
        for (int j = 0; j < 8; ++j) {
            const int k = st * 32 + g * 8 + j;
            const int e = k >> 2, c = k & 3, dx = e - s;
            const float wv = (dx >= 0 && dx < 11)
                ? s_wc[((dy * 11 + dx) * 4 + c) * 4 + f] : 0.f;
            const f16x2 hlv = split_f(wv);
            v[j] = hl ? hlv[1] : hlv[0];
        }
        fragW2[((size_t)b * 11 + dy) * 256 + rem] = v;
    }

    // B-fragments for W1 (batch-independent; block 0 only)
    if (b == 0) {
        for (int fi = t; fi < 9 * 256; fi += 256) {
            const int dy = fi >> 8, rem = fi & 255;
            const int st = (rem >> 7) & 1, hl = (rem >> 6) & 1, lane = rem & 63;
            const int g = lane >> 4, n = lane & 15, s = n >> 2, f = n & 3;
            f16x8 v;
#pragma unroll
            for (int j = 0; j < 8; ++j) {
                const int k = st * 32 + g * 8 + j;
                const int e = k >> 2, c = k & 3, dx = e - s;
                const float wv = (dx >= 0 && dx < 9)
                    ? W1[((dy * 9 + dx) * 4 + c) * 4 + f] : 0.f;
                const f16x2 hlv = split_f(wv);
                v[j] = hl ? hlv[1] : hlv[0];
            }
            fragW1[(size_t)dy * 256 + rem] = v;
        }
    }
}

// --- conv1: [16,512,512,4] f32 -> relu -> y1 [16,504,504] x (h,l)x4 f16
//     16-row tiles: LDS 24x76x16B = 29.2KB -> 5 blocks/CU
__global__ __launch_bounds__(256, 2) void k_conv1(
    const float* __restrict__ in, const float* __restrict__ b1,
    const f16x8* __restrict__ fragW1, f16* __restrict__ y1)
{
    __shared__ f16x4 s_hi[24][76];
    __shared__ f16x4 s_lo[24][76];
    const int t = threadIdx.x;
    const int x0 = blockIdx.x * 64, y0 = blockIdx.y * 16, b = blockIdx.z;

    const float4* inp = (const float4*)in + (size_t)b * (512 * 512);
    for (int i = t; i < 24 * 76; i += 256) {
        const int rr = i / 76, cc = i % 76;
        const int gy = y0 + rr, gx = x0 + cc;
        float4 v = make_float4(0.f, 0.f, 0.f, 0.f);
        if (gy < 512 && gx < 512) v = inp[gy * 512 + gx];
        f16x4 h, l;
        const f16x2 p0 = split_f(v.x), p1 = split_f(v.y);
        const f16x2 p2 = split_f(v.z), p3 = split_f(v.w);
        h[0] = p0[0]; l[0] = p0[1]; h[1] = p1[0]; l[1] = p1[1];
        h[2] = p2[0]; l[2] = p2[1]; h[3] = p3[0]; l[3] = p3[1];
        s_hi[rr][cc] = h; s_lo[rr][cc] = l;
    }

    const int lane = t & 63, w = t >> 6;
    const int g = lane >> 4, n = lane & 15, s = n >> 2, f = n & 3;

    __syncthreads();

    const float bias = b1[f];
    f32x4 acc[4];
#pragma unroll
    for (int r = 0; r < 4; ++r) acc[r] = (f32x4){bias, bias, bias, bias};

    const int ai = 4 * (lane & 15) + 2 * g;
#pragma unroll
    for (int st = 0; st < 2; ++st) {
        const f16x8* bbase = fragW1 + st * 128 + lane;
        const int aoff = ai + st * 8;
        conv_chunk4<0, 5, 24>(bbase, s_hi, s_lo, w * 4, aoff, acc);
        conv_chunk4<5, 4, 24>(bbase, s_hi, s_lo, w * 4, aoff, acc);
    }

    // D: col n=(s,f); row m=4g+q; x = x0+16g+4q+s; store (h,l) f16x2
    const int xb = x0 + 16 * g + s;
#pragma unroll
    for (int r = 0; r < 4; ++r) {
        const int yr = y0 + w * 4 + r;
        if (yr >= 504) continue;
        const size_t rowbase = ((size_t)(b * 504 + yr) * 504) * 8 + f * 2;
#pragma unroll
        for (int q = 0; q < 4; ++q) {
            const int x = xb + 4 * q;
            if (x < 504) {
                const float v = fmaxf(acc[r][q], 0.f);
                *(f16x2*)(y1 + rowbase + (size_t)x * 8) = split_f(v);
            }
        }
    }
}

// --- composite 11x11 per-batch conv on y1 + relu + pixnorm -> out f32
//     16-row tiles: LDS 26x76x16B = 31.6KB -> 5 blocks/CU
__global__ __launch_bounds__(256, 2) void k_dwconv2(
    const f16* __restrict__ y1, const float* __restrict__ b2,
    const f16x8* __restrict__ fragW2, float* __restrict__ out)
{
    __shared__ f16x4 s_hi[26][76];
    __shared__ f16x4 s_lo[26][76];
    const int t = threadIdx.x;
    const int x0 = blockIdx.x * 64, y0 = blockIdx.y * 16, b = blockIdx.z;

    // stage y1 with halo (-1 .. +9 beyond tile), zero outside [0,504)^2
    for (int i = t; i < 26 * 76; i += 256) {
        const int rr = i / 76, cc = i % 76;
        const int gy = y0 - 1 + rr, gx = x0 - 1 + cc;
        f16x4 h, l;
        if (gy >= 0 && gy < 504 && gx >= 0 && gx < 504) {
            const f16x8 p = *(const f16x8*)(y1 + ((size_t)(b * 504 + gy) * 504 +
                                                  (size_t)gx) * 8);
            h[0] = p[0]; l[0] = p[1]; h[1] = p[2]; l[1] = p[3];
            h[2] = p[4]; l[2] = p[5]; h[3] = p[6]; l[3] = p[7];
        } else {
            h[0] = h[1] = h[2] = h[3] = (f16)0.f;
            l[0] = l[1] = l[2] = l[3] = (f16)0.f;
        }
        s_hi[rr][cc] = h; s_lo[rr][cc] = l;
    }

    const int lane = t & 63, w = t >> 6;
    const int g = lane >> 4, n = lane & 15, s = n >> 2, f = n & 3;
    const f16x8* fr = fragW2 + (size_t)b * 11 * 256;

    __syncthreads();

    const float bias = b2[f];
    f32x4 acc[4];
#pragma unroll
    for (int r = 0; r < 4; ++r) acc[r] = (f32x4){bias, bias, bias, bias};

    const int ai = 4 * (lane & 15) + 2 * g;
#pragma unroll
    for (int st = 0; st < 2; ++st) {
        const f16x8* bbase = fr + st * 128 + lane;
        const int aoff = ai + st * 8;
        conv_chunk4<0, 4, 26>(bbase, s_hi, s_lo, w * 4, aoff, acc);
        conv_chunk4<4, 4, 26>(bbase, s_hi, s_lo, w * 4, aoff, acc);
        conv_chunk4<8, 3, 26>(bbase, s_hi, s_lo, w * 4, aoff, acc);
    }

    // epilogue: relu -> pixnorm across channels (lanes n^1, n^2) -> f32 store
    const int xb = x0 + 16 * g + s;
#pragma unroll
    for (int r = 0; r < 4; ++r) {
        const int yr = y0 + w * 4 + r;
        const size_t rowbase = ((size_t)((size_t)b * 496 + yr) * 496) * 4 + f;
#pragma unroll
        for (int q = 0; q < 4; ++q) {
            float v = fmaxf(acc[r][q], 0.f);
            float sq = v * v;
            sq += __shfl_xor(sq, 1);
            sq += __shfl_xor(sq, 2);
            const float sc = rsqrtf(sq * 0.25f + 1e-8f);
            const int x = xb + 4 * q;
            if (yr < 496 && x < 496) out[rowbase + (size_t)x * 4] = v * sc;
        }
    }
}

extern "C" void kernel_launch(void* const* d_in, const int* in_sizes, int n_in,
                              void* d_out, int out_size, void* d_ws, size_t ws_size,
                              hipStream_t stream)
{
    const float* noise  = (const float*)d_in[0];
    const float* params = (const float*)d_in[1];
    const float* W_emb  = (const float*)d_in[2];
    const float* b_emb  = (const float*)d_in[3];
    const float* KT     = (const float*)d_in[4];
    const float* bT     = (const float*)d_in[5];
    const float* W1     = (const float*)d_in[6];
    const float* b1     = (const float*)d_in[7];
    const float* W2     = (const float*)d_in[8];
    const float* b2     = (const float*)d_in[9];

    float* out = (float*)d_out;
    f16*   y1  = (f16*)d_ws;  // 16*504*504*8 f16 = 65,028,096 B
    f16x8* fragW2 = (f16x8*)((char*)d_ws + 65028096);           // 720,896 B
    f16x8* fragW1 = (f16x8*)((char*)d_ws + 65028096 + 720896);  //  36,864 B

    k_prep<<<dim3(16), dim3(256), 0, stream>>>(params, W_emb, b_emb, KT, bT,
                                               W1, W2, fragW1, fragW2);

    dim3 grid(8, 32, 16);   // ceil(504/64), ceil(504/16), B
    k_conv1<<<grid, dim3(256), 0, stream>>>(noise, b1, fragW1, y1);

    dim3 grid2(8, 31, 16);  // ceil(496/64), 496/16, B
    k_dwconv2<<<grid2, dim3(256), 0, stream>>>(y1, b2, fragW2, out);
}